// Round 5
// baseline (293.244 us; speedup 1.0000x reference)
//
#include <hip/hip_runtime.h>
#include <cstddef>
#include <cstdint>

// Problem constants (match reference)
#define BB 16
#define NN 33600
#define CC 80
#define MAXN 100
#define NBINS 4096
#define MAXC 1024
#define SCORE_THR_F 0.05f
#define IOU_THR_F 0.65f

#define NCHUNK 525            // NN / 64 row-tiles of 64 rows
#define K1_TPB 4              // tiles per block
#define K1_GX ((NCHUNK + K1_TPB - 1) / K1_TPB)  // 132
#define TILE_F4 (64 * CC / 4)  // 1280 float4 = 20 KB per tile
#define K2T 512               // k2 threads

// ws layout: masked [B*N floats] then ghist [B*NBINS ints]
#define OFF_GHIST (BB * NN * 4)

__global__ __launch_bounds__(256) void k0_zero(int* __restrict__ p) {
  int i = blockIdx.x * 256 + threadIdx.x;
  if (i < BB * NBINS) p[i] = 0;
}

// K1: LDS-staged, fully-contiguous global loads. Each tile = 64 rows (20 KB),
// staged by the whole block (1 KB contiguous per wave instruction), then
// 4 threads/row reduce from LDS (2-way bank aliasing — free). Also builds the
// per-batch score histogram via device-scope atomics (~8 adds/bin).
__global__ __launch_bounds__(256) void k1_score(const float* __restrict__ cls,
                                                const float* __restrict__ obj,
                                                float* __restrict__ masked,
                                                int* __restrict__ ghist) {
  const int b = blockIdx.y;
  const int tid = threadIdx.x;
  const int q = tid & 3;
  const int r = tid >> 2;  // 0..63
  __shared__ float4 st[TILE_F4];

  for (int ti = 0; ti < K1_TPB; ti++) {
    const int tile = blockIdx.x * K1_TPB + ti;
    if (tile >= NCHUNK) break;
    const int n0 = tile * 64;
    const float4* src = (const float4*)(cls + ((size_t)b * NN + n0) * CC);
    __syncthreads();  // protect st against previous iteration's readers
#pragma unroll
    for (int j = 0; j < 5; j++) st[j * 256 + tid] = src[j * 256 + tid];
    __syncthreads();

    const float* rowp = (const float*)st + r * CC;
    float m = -INFINITY;
#pragma unroll
    for (int j = 0; j < 5; j++) {
      float4 v = *(const float4*)(rowp + (q + 4 * j) * 4);
      m = fmaxf(m, fmaxf(fmaxf(v.x, v.y), fmaxf(v.z, v.w)));
    }
#pragma unroll
    for (int d = 1; d < 4; d <<= 1) m = fmaxf(m, __shfl_xor(m, d, 4));
    if (q == 0) {
      const int n = n0 + r;
      float o = obj[(size_t)b * NN + n];
      float s = (1.0f / (1.0f + expf(-m))) * (1.0f / (1.0f + expf(-o)));
      bool valid = (s >= SCORE_THR_F);
      masked[(size_t)b * NN + n] = valid ? s : -INFINITY;
      if (valid) {
        int bin = min(NBINS - 1, (int)(s * (float)NBINS));
        atomicAdd(&ghist[b * NBINS + bin], 1);
      }
    }
  }
}

__device__ __forceinline__ int score_bin(float s) {
  return min(NBINS - 1, (int)(s * (float)NBINS));
}

// K2: one block per batch. Load histogram -> threshold -> compact -> rank-select
// top-100 -> decode+label -> pairwise suppression bitmask -> greedy scan -> write.
__global__ __launch_bounds__(K2T) void k2_all(const float* __restrict__ cls,
                                              const float* __restrict__ bbox,
                                              const float* __restrict__ priors,
                                              const float* __restrict__ masked,
                                              const int* __restrict__ ghist,
                                              float* __restrict__ out) {
  const int b = blockIdx.x;
  const int tid = threadIdx.x;

  __shared__ int hist[NBINS];
  __shared__ int sfx[K2T];
  __shared__ int s_t, s_cnt;
  __shared__ float cs[MAXC];
  __shared__ int ci[MAXC];
  __shared__ int sel[MAXN];               // original anchor index, -1 if empty
  __shared__ float sb[MAXN][4];           // x1,y1,x2,y2
  __shared__ float ssc[MAXN];
  __shared__ int slab[MAXN];
  __shared__ unsigned int sup[MAXN][4];   // suppression bitmask (j bits), j>i only
  __shared__ unsigned int keepw[4];

  const float4* msc4 = (const float4*)(masked + (size_t)b * NN);

  for (int i = tid; i < NBINS; i += K2T) hist[i] = ghist[b * NBINS + i];
  if (tid == 0) { s_t = 0; s_cnt = 0; }
  __syncthreads();

  // Parallel suffix scan: largest bin t with suffix count >= MAXN (0 if < MAXN valid)
  int sum = 0;
#pragma unroll
  for (int j = 0; j < NBINS / K2T; j++) sum += hist[tid * (NBINS / K2T) + j];
  sfx[tid] = sum;
  __syncthreads();
  for (int off = 1; off < K2T; off <<= 1) {
    int v = sfx[tid];
    int add = (tid + off < K2T) ? sfx[tid + off] : 0;
    __syncthreads();
    sfx[tid] = v + add;
    __syncthreads();
  }
  {
    int Sc = sfx[tid];
    int Sn = (tid < K2T - 1) ? sfx[tid + 1] : 0;
    if (Sc >= MAXN && Sn < MAXN) {
      int running = Sn;
      const int lo = tid * (NBINS / K2T);
      for (int bin = lo + (NBINS / K2T) - 1; bin >= lo; bin--) {
        running += hist[bin];
        if (running >= MAXN) { s_t = bin; break; }
      }
    }
  }
  __syncthreads();
  const int t = s_t;

  // Compact candidates with bin >= t into LDS (masked is L2-hot)
  for (int i = tid; i < NN / 4; i += K2T) {
    float4 v = msc4[i];
    int base = i * 4;
    if (v.x >= SCORE_THR_F && score_bin(v.x) >= t) {
      int p = atomicAdd(&s_cnt, 1); if (p < MAXC) { cs[p] = v.x; ci[p] = base; }
    }
    if (v.y >= SCORE_THR_F && score_bin(v.y) >= t) {
      int p = atomicAdd(&s_cnt, 1); if (p < MAXC) { cs[p] = v.y; ci[p] = base + 1; }
    }
    if (v.z >= SCORE_THR_F && score_bin(v.z) >= t) {
      int p = atomicAdd(&s_cnt, 1); if (p < MAXC) { cs[p] = v.z; ci[p] = base + 2; }
    }
    if (v.w >= SCORE_THR_F && score_bin(v.w) >= t) {
      int p = atomicAdd(&s_cnt, 1); if (p < MAXC) { cs[p] = v.w; ci[p] = base + 3; }
    }
  }
  __syncthreads();
  const int C = min(s_cnt, MAXC);

  for (int k = tid; k < MAXN; k += K2T) sel[k] = -1;
  __syncthreads();

  // Rank by counting: rank = #{j : (s_j,i_j) before (s_i,i_i)}; ranks are unique
  // (descending score, ascending index on ties — stable argsort semantics).
  for (int i = tid; i < C; i += K2T) {
    float si = cs[i]; int ii = ci[i];
    int r = 0;
    for (int j = 0; j < C; j++) {
      float sj = cs[j]; int ij = ci[j];
      r += (sj > si) || (sj == si && ij < ii);
    }
    if (r < MAXN) { sel[r] = ii; ssc[r] = si; }
  }
  __syncthreads();

  // Decode + label for the <=100 winners; zero suppression masks in parallel
  if (tid < MAXN) {
    int idx = sel[tid];
    if (idx >= 0) {
      float4 p = ((const float4*)priors)[idx];                 // [x*s, y*s, s, s]
      float4 d = ((const float4*)bbox)[(size_t)b * NN + idx];  // [dx, dy, dw, dh]
      float cx = d.x * p.z + p.x;
      float cy = d.y * p.w + p.y;
      float hw = expf(d.z) * p.z * 0.5f;
      float hh = expf(d.w) * p.w * 0.5f;
      sb[tid][0] = cx - hw; sb[tid][1] = cy - hh;
      sb[tid][2] = cx + hw; sb[tid][3] = cy + hh;
      const float4* crow = (const float4*)(cls + ((size_t)b * NN + idx) * CC);
      float m = -INFINITY; int lab = 0;
#pragma unroll 4
      for (int j = 0; j < CC / 4; j++) {
        float4 v = crow[j];
        int c0 = 4 * j;
        if (v.x > m) { m = v.x; lab = c0; }      // first occurrence on ties,
        if (v.y > m) { m = v.y; lab = c0 + 1; }  // like jnp.argmax
        if (v.z > m) { m = v.z; lab = c0 + 2; }
        if (v.w > m) { m = v.w; lab = c0 + 3; }
      }
      slab[tid] = lab;
    } else {
      sb[tid][0] = 0.f; sb[tid][1] = 0.f; sb[tid][2] = 0.f; sb[tid][3] = 0.f;
      ssc[tid] = 0.f; slab[tid] = -1;
    }
  }
  for (int i = tid; i < MAXN * 4; i += K2T) ((unsigned int*)sup)[i] = 0;
  __syncthreads();

  // Pairwise IOUs -> suppression bitmask (only j > i, same label, iou >= thr)
  for (int p = tid; p < MAXN * MAXN; p += K2T) {
    int i = p / MAXN, j = p % MAXN;
    if (j > i && sel[i] >= 0 && sel[j] >= 0 && slab[i] == slab[j]) {
      float xx1 = fmaxf(sb[i][0], sb[j][0]);
      float yy1 = fmaxf(sb[i][1], sb[j][1]);
      float xx2 = fminf(sb[i][2], sb[j][2]);
      float yy2 = fminf(sb[i][3], sb[j][3]);
      float inter = fmaxf(xx2 - xx1, 0.f) * fmaxf(yy2 - yy1, 0.f);
      float ai = (sb[i][2] - sb[i][0]) * (sb[i][3] - sb[i][1]);
      float aj = (sb[j][2] - sb[j][0]) * (sb[j][3] - sb[j][1]);
      float iou = inter / (ai + aj - inter + 1e-8f);
      if (iou >= IOU_THR_F) atomicOr(&sup[i][j >> 5], 1u << (j & 31));
    }
  }
  __syncthreads();

  // Greedy scan in one thread over register bitmask (~100 trivial iterations)
  if (tid == 0) {
    unsigned int kw0 = 0, kw1 = 0, kw2 = 0, kw3 = 0;
    for (int k = 0; k < MAXN; k++)
      if (sel[k] >= 0) {
        if (k < 32) kw0 |= 1u << k;
        else if (k < 64) kw1 |= 1u << (k - 32);
        else if (k < 96) kw2 |= 1u << (k - 64);
        else kw3 |= 1u << (k - 96);
      }
    for (int i = 0; i < MAXN; i++) {
      unsigned int bit = (i < 32) ? (kw0 >> i) : (i < 64) ? (kw1 >> (i - 32))
                        : (i < 96) ? (kw2 >> (i - 64)) : (kw3 >> (i - 96));
      if (bit & 1u) {
        kw0 &= ~sup[i][0]; kw1 &= ~sup[i][1];
        kw2 &= ~sup[i][2]; kw3 &= ~sup[i][3];
      }
    }
    keepw[0] = kw0; keepw[1] = kw1; keepw[2] = kw2; keepw[3] = kw3;
  }
  __syncthreads();

  // Write output: dets [B,100,6] then keep [B,100] as 0.0/1.0
  if (tid < MAXN) {
    int k = tid;
    bool kp = (keepw[k >> 5] >> (k & 31)) & 1u;
    float* row = out + ((size_t)b * MAXN + k) * 6;
    if (kp) {
      row[0] = sb[k][0]; row[1] = sb[k][1]; row[2] = sb[k][2]; row[3] = sb[k][3];
      row[4] = ssc[k];   row[5] = (float)slab[k];
    } else {
      row[0] = 0.f; row[1] = 0.f; row[2] = 0.f; row[3] = 0.f;
      row[4] = 0.f; row[5] = -1.f;
    }
    out[(size_t)BB * MAXN * 6 + (size_t)b * MAXN + k] = kp ? 1.0f : 0.0f;
  }
}

extern "C" void kernel_launch(void* const* d_in, const int* in_sizes, int n_in,
                              void* d_out, int out_size, void* d_ws, size_t ws_size,
                              hipStream_t stream) {
  const float* cls    = (const float*)d_in[0];  // [B,N,C]
  const float* bbox   = (const float*)d_in[1];  // [B,N,4]
  const float* obj    = (const float*)d_in[2];  // [B,N]
  const float* priors = (const float*)d_in[3];  // [N,4]
  float* out = (float*)d_out;                   // [B,100,6] ++ [B,100]

  char* ws = (char*)d_ws;
  float* masked = (float*)ws;                   // [B,N] masked scores (2.15 MB)
  int* ghist = (int*)(ws + OFF_GHIST);          // [B,NBINS] (256 KB)

  k0_zero<<<(BB * NBINS + 255) / 256, 256, 0, stream>>>(ghist);
  k1_score<<<dim3(K1_GX, BB), 256, 0, stream>>>(cls, obj, masked, ghist);
  k2_all<<<BB, K2T, 0, stream>>>(cls, bbox, priors, masked, ghist, out);
}